// Round 12
// baseline (240.894 us; speedup 1.0000x reference)
//
#include <hip/hip_runtime.h>
#include <hip/hip_bf16.h>
#include <cstddef>

#define T_SEQ 2048
#define D_HEAD 64
#define BC 64
#define NKT (T_SEQ / BC)
#define PAD 72           // LDS row stride elems (144 B, 16B-aligned)
#define NTHR 128         // 2 waves per block

typedef __bf16 bf16x8 __attribute__((ext_vector_type(8)));
typedef float f32x4 __attribute__((ext_vector_type(4)));
typedef unsigned short u16x8 __attribute__((ext_vector_type(8)));

__device__ __forceinline__ unsigned short f2bf(float f) {
  __bf16 h = (__bf16)f;
  return __builtin_bit_cast(unsigned short, h);
}
__device__ __forceinline__ bf16x8 ldfrag(const unsigned short* p) {
  u16x8 t = *(const u16x8*)p;
  return __builtin_bit_cast(bf16x8, t);
}
__device__ __forceinline__ f32x4 mfma16(bf16x8 a, bf16x8 b, f32x4 c) {
  return __builtin_amdgcn_mfma_f32_16x16x32_bf16(a, b, c, 0, 0, 0);
}
__device__ __forceinline__ void bar_sync() {
  asm volatile("" ::: "memory");
  __builtin_amdgcn_s_barrier();
  asm volatile("" ::: "memory");
}
__device__ __forceinline__ void lds_fence() {
  asm volatile("s_waitcnt lgkmcnt(0)" ::: "memory");
}
__device__ __forceinline__ float exp2_hw(float x) { return __builtin_amdgcn_exp2f(x); }
__device__ __forceinline__ float log2_hw(float x) { return __builtin_amdgcn_logf(x); }

// ---------- mask pack: (T,T) int32 {0,1} -> 1 bit/elem ----------
__global__ __launch_bounds__(256) void mask_pack(const int* __restrict__ maskg,
                                                 unsigned* __restrict__ mp) {
  const size_t total = (size_t)T_SEQ * T_SEQ;
  size_t idx = (size_t)blockIdx.x * blockDim.x + threadIdx.x;
  const size_t stride = (size_t)gridDim.x * blockDim.x;
  const int lane = threadIdx.x & 63;
  for (; idx < total; idx += stride) {
    int mv = maskg[idx];
    unsigned long long b = __ballot(mv != 0);
    if (lane == 0)       mp[idx >> 5] = (unsigned)b;
    else if (lane == 32) mp[idx >> 5] = (unsigned)(b >> 32);
  }
}

// ---------- 32-rows-per-wave fused attention (2 waves/block, frag reuse x2) ----------
// frag convention (verified R1-R9): A/B-frag row=lane&15, k=kk*32+8*(lane>>4)+[0..7]
// mfma(A,B): D[aidx][bidx], row=4*(lane>>4)+reg -> aidx, col=lane&15 -> bidx
__global__ __launch_bounds__(NTHR, 2) void attn_fused5(
    const float* __restrict__ qg, const float* __restrict__ kg,
    const float* __restrict__ vg, const unsigned* __restrict__ mpk,
    float* __restrict__ outg, float* __restrict__ attng)
{
  __shared__ unsigned short ks[BC][PAD];      // K tile bf16 [key][d]
  __shared__ unsigned short vt[D_HEAD][PAD];  // V^T tile bf16 [d][key]
  __shared__ unsigned short ps[64][PAD];      // P strips: wave w rows [w*32, w*32+32)

  const int bid = blockIdx.x;
  const int lin = (bid & 7) * 128 + (bid >> 3);   // XCD-chunked: 4 heads/XCD
  const int bh  = lin >> 5;                       // head 0..31
  const int blk64 = (lin & 31) * 64;              // block's 64-row base (head-local)

  const int tid  = threadIdx.x;                   // 0..127
  const int lane = tid & 63;
  const int wid  = tid >> 6;                      // 0..1
  const int lr = lane & 15, lh = lane >> 4;
  const int r0s0 = blk64 + wid * 32;              // strip 0 base (16 rows)
  const int r0s1 = r0s0 + 16;                     // strip 1 base
  const int sv = tid >> 2;                        // K staging row 0..31 (+32)
  const int sc4 = (tid & 3) << 4;                 // K staging col {0,16,32,48}
  const int vt7 = tid & 7;                        // V staging: d = vt7 + 8j
  const int vs2 = (tid >> 3) * 2;                 // V staging: s pair 0..30 (+32)

  const float C = 0.18033688011112042f;           // 0.125 * log2(e)
  const float* qb = qg + (size_t)bh * T_SEQ * D_HEAD;
  const float* kb = kg + (size_t)bh * T_SEQ * D_HEAD;
  const float* vb = vg + (size_t)bh * T_SEQ * D_HEAD;
  const int ROWW = T_SEQ / 32;
  const f32x4 zero4 = {0.f, 0.f, 0.f, 0.f};

  // ---- Q frags for both strips (once) ----
  bf16x8 qf[2][2];   // [strip][kk]
  #pragma unroll
  for (int s = 0; s < 2; ++s) {
    const float* qr = qb + (size_t)((s ? r0s1 : r0s0) + lr) * D_HEAD;
    #pragma unroll
    for (int kk = 0; kk < 2; ++kk) {
      float4 a = *(const float4*)(qr + kk * 32 + lh * 8);
      float4 b = *(const float4*)(qr + kk * 32 + lh * 8 + 4);
      u16x8 u;
      u[0] = f2bf(a.x); u[1] = f2bf(a.y); u[2] = f2bf(a.z); u[3] = f2bf(a.w);
      u[4] = f2bf(b.x); u[5] = f2bf(b.y); u[6] = f2bf(b.z); u[7] = f2bf(b.w);
      qf[s][kk] = __builtin_bit_cast(bf16x8, u);
    }
  }

  f32x4 acc[2][4];   // [strip][nt]
  #pragma unroll
  for (int s = 0; s < 2; ++s)
    #pragma unroll
    for (int nt = 0; nt < 4; ++nt) acc[s][nt] = zero4;
  float psum[2] = {0.f, 0.f};

  // =================== PASS 1 (swapped QK^T, 2 barriers/tile) ===================
  for (int kt = 0; kt < NKT; ++kt) {
    const int n0 = kt * BC;
    bar_sync();                                  // LDS free
    // stage K (b128 writes) + V^T (packed b32) — 2 sub-iters (128 threads)
    #pragma unroll
    for (int it = 0; it < 2; ++it) {
      const int row = sv + it * 32;
      const float* ksrc = kb + (size_t)(n0 + row) * D_HEAD + sc4;
      float4 k0 = *(const float4*)(ksrc + 0),  k1 = *(const float4*)(ksrc + 4);
      float4 k2 = *(const float4*)(ksrc + 8),  k3 = *(const float4*)(ksrc + 12);
      u16x8 w0, w1;
      w0[0]=f2bf(k0.x); w0[1]=f2bf(k0.y); w0[2]=f2bf(k0.z); w0[3]=f2bf(k0.w);
      w0[4]=f2bf(k1.x); w0[5]=f2bf(k1.y); w0[6]=f2bf(k1.z); w0[7]=f2bf(k1.w);
      w1[0]=f2bf(k2.x); w1[1]=f2bf(k2.y); w1[2]=f2bf(k2.z); w1[3]=f2bf(k2.w);
      w1[4]=f2bf(k3.x); w1[5]=f2bf(k3.y); w1[6]=f2bf(k3.z); w1[7]=f2bf(k3.w);
      *(u16x8*)&ks[row][sc4 + 0] = w0;
      *(u16x8*)&ks[row][sc4 + 8] = w1;
      const int s0 = vs2 + it * 32;
      const float* v0p = vb + (size_t)(n0 + s0) * D_HEAD + vt7;
      const float* v1p = v0p + D_HEAD;
      #pragma unroll
      for (int j = 0; j < 8; ++j) {
        const unsigned w = (unsigned)f2bf(v0p[8 * j]) | ((unsigned)f2bf(v1p[8 * j]) << 16);
        *(unsigned*)&vt[vt7 + 8 * j][s0] = w;
      }
    }
    // masks for both strips (q = r0 + lr)
    const unsigned m00 = mpk[(size_t)(r0s0 + lr) * ROWW + kt * 2];
    const unsigned m01 = mpk[(size_t)(r0s0 + lr) * ROWW + kt * 2 + 1];
    const unsigned m10 = mpk[(size_t)(r0s1 + lr) * ROWW + kt * 2];
    const unsigned m11 = mpk[(size_t)(r0s1 + lr) * ROWW + kt * 2 + 1];
    lds_fence(); bar_sync();                     // tile ready

    // swapped QK^T: kf shared by both strips (8 reads -> 16 MFMAs)
    f32x4 st[2][4];
    #pragma unroll
    for (int s = 0; s < 2; ++s)
      #pragma unroll
      for (int nt = 0; nt < 4; ++nt) st[s][nt] = zero4;
    #pragma unroll
    for (int kk = 0; kk < 2; ++kk) {
      bf16x8 kf[4];
      #pragma unroll
      for (int nt = 0; nt < 4; ++nt) kf[nt] = ldfrag(&ks[nt * 16 + lr][kk * 32 + lh * 8]);
      #pragma unroll
      for (int nt = 0; nt < 4; ++nt) {
        st[0][nt] = mfma16(kf[nt], qf[0][kk], st[0][nt]);
        st[1][nt] = mfma16(kf[nt], qf[1][kk], st[1][nt]);
      }
    }
    // exp + psum + packed b64 P writes (wave-private rows)
    #pragma unroll
    for (int s = 0; s < 2; ++s) {
      const unsigned w0m = s ? m10 : m00;
      const unsigned w1m = s ? m11 : m01;
      #pragma unroll
      for (int nt = 0; nt < 4; ++nt) {
        const unsigned w = (nt & 2) ? w1m : w0m;
        float p[4];
        #pragma unroll
        for (int r = 0; r < 4; ++r) {
          const int bit = (nt & 1) * 16 + 4 * lh + r;
          p[r] = ((w >> bit) & 1) ? exp2_hw(st[s][nt][r] * C) : 0.f;
          psum[s] += p[r];
        }
        uint2 u;
        u.x = (unsigned)f2bf(p[0]) | ((unsigned)f2bf(p[1]) << 16);
        u.y = (unsigned)f2bf(p[2]) | ((unsigned)f2bf(p[3]) << 16);
        *(uint2*)&ps[wid * 32 + s * 16 + lr][nt * 16 + 4 * lh] = u;
      }
    }
    lds_fence();                                 // wave-private write->read
    // PV: vf shared by both strips (8 reads -> 16 MFMAs)
    #pragma unroll
    for (int kk = 0; kk < 2; ++kk) {
      const bf16x8 pa0 = ldfrag(&ps[wid * 32 + lr][kk * 32 + lh * 8]);
      const bf16x8 pa1 = ldfrag(&ps[wid * 32 + 16 + lr][kk * 32 + lh * 8]);
      #pragma unroll
      for (int nt = 0; nt < 4; ++nt) {
        const bf16x8 vf = ldfrag(&vt[nt * 16 + lr][kk * 32 + lh * 8]);
        acc[0][nt] = mfma16(pa0, vf, acc[0][nt]);
        acc[1][nt] = mfma16(pa1, vf, acc[1][nt]);
      }
    }
  }

  // rowsum + O per strip
  float lg2ivq[2][4];
  #pragma unroll
  for (int s = 0; s < 2; ++s) {
    float ssum = psum[s];
    ssum += __shfl_xor(ssum, 16);
    ssum += __shfl_xor(ssum, 32);
    const float iv_s = 1.0f / ssum;
    float ivq[4];
    #pragma unroll
    for (int r = 0; r < 4; ++r) {
      ivq[r] = __shfl(iv_s, 4 * lh + r);
      lg2ivq[s][r] = log2_hw(ivq[r]);
    }
    float* ob = outg + (size_t)(bh * T_SEQ + (s ? r0s1 : r0s0)) * D_HEAD;
    #pragma unroll
    for (int nt = 0; nt < 4; ++nt)
      #pragma unroll
      for (int r = 0; r < 4; ++r)
        ob[(size_t)(4 * lh + r) * D_HEAD + nt * 16 + lr] = acc[s][nt][r] * ivq[r];
  }

  // =================== PASS 2 (direct QK^T, kf shared by strips) ===================
  float* ab0 = attng + (size_t)(bh * T_SEQ + r0s0) * T_SEQ;
  float* ab1 = attng + (size_t)(bh * T_SEQ + r0s1) * T_SEQ;
  for (int kt = 0; kt < NKT; ++kt) {
    const int n0 = kt * BC;
    bar_sync();
    #pragma unroll
    for (int it = 0; it < 2; ++it) {
      const int row = sv + it * 32;
      const float* ksrc = kb + (size_t)(n0 + row) * D_HEAD + sc4;
      float4 k0 = *(const float4*)(ksrc + 0),  k1 = *(const float4*)(ksrc + 4);
      float4 k2 = *(const float4*)(ksrc + 8),  k3 = *(const float4*)(ksrc + 12);
      u16x8 w0, w1;
      w0[0]=f2bf(k0.x); w0[1]=f2bf(k0.y); w0[2]=f2bf(k0.z); w0[3]=f2bf(k0.w);
      w0[4]=f2bf(k1.x); w0[5]=f2bf(k1.y); w0[6]=f2bf(k1.z); w0[7]=f2bf(k1.w);
      w1[0]=f2bf(k2.x); w1[1]=f2bf(k2.y); w1[2]=f2bf(k2.z); w1[3]=f2bf(k2.w);
      w1[4]=f2bf(k3.x); w1[5]=f2bf(k3.y); w1[6]=f2bf(k3.z); w1[7]=f2bf(k3.w);
      *(u16x8*)&ks[row][sc4 + 0] = w0;
      *(u16x8*)&ks[row][sc4 + 8] = w1;
    }
    unsigned mw[2][4][2];
    #pragma unroll
    for (int s = 0; s < 2; ++s)
      #pragma unroll
      for (int r = 0; r < 4; ++r) {
        const size_t mrow = (size_t)((s ? r0s1 : r0s0) + 4 * lh + r) * ROWW + kt * 2;
        mw[s][r][0] = mpk[mrow];
        mw[s][r][1] = mpk[mrow + 1];
      }
    lds_fence(); bar_sync();

    f32x4 sc_[2][4];
    #pragma unroll
    for (int s = 0; s < 2; ++s)
      #pragma unroll
      for (int nt = 0; nt < 4; ++nt) sc_[s][nt] = zero4;
    #pragma unroll
    for (int kk = 0; kk < 2; ++kk) {
      bf16x8 kf[4];
      #pragma unroll
      for (int nt = 0; nt < 4; ++nt) kf[nt] = ldfrag(&ks[nt * 16 + lr][kk * 32 + lh * 8]);
      #pragma unroll
      for (int nt = 0; nt < 4; ++nt) {
        sc_[0][nt] = mfma16(qf[0][kk], kf[nt], sc_[0][nt]);
        sc_[1][nt] = mfma16(qf[1][kk], kf[nt], sc_[1][nt]);
      }
    }
    #pragma unroll
    for (int s = 0; s < 2; ++s) {
      float* ab = s ? ab1 : ab0;
      #pragma unroll
      for (int r = 0; r < 4; ++r) {
        float* arow = ab + (size_t)(4 * lh + r) * T_SEQ + n0;
        #pragma unroll
        for (int nt = 0; nt < 4; ++nt) {
          const int mv = (mw[s][r][nt >> 1] >> ((nt & 1) * 16 + lr)) & 1;
          const float p = mv ? exp2_hw(__builtin_fmaf(sc_[s][nt][r], C, lg2ivq[s][r])) : 0.f;
          __builtin_nontemporal_store(p, arow + nt * 16 + lr);
        }
      }
    }
  }
}

// ---------- fallback: fused single kernel, raw mask (ws too small) ----------
__global__ __launch_bounds__(512, 2) void attn_fused_fb(
    const float* __restrict__ qg, const float* __restrict__ kg,
    const float* __restrict__ vg, const int* __restrict__ maskg,
    float* __restrict__ outg, float* __restrict__ attng)
{
  __shared__ unsigned short qs[128][PAD];
  __shared__ unsigned short ks[64][PAD];
  __shared__ unsigned short vt[64][PAD];
  __shared__ unsigned short pp[128][PAD];
  __shared__ float rsum[128];
  int bid = blockIdx.x;
  int lin = (bid & 7) * 64 + (bid >> 3);
  int bh = lin >> 4, br0 = (lin & 15) * 128;
  const int tid = threadIdx.x, lane = tid & 63, wid = tid >> 6;
  const int wm = wid >> 1, wn = wid & 1, lr = lane & 15, lh = lane >> 4;
  const float scale = 0.125f;
  const float* qb = qg + ((size_t)bh * T_SEQ + br0) * D_HEAD;
  const float* kbp = kg + (size_t)bh * T_SEQ * D_HEAD;
  const float* vbp = vg + (size_t)bh * T_SEQ * D_HEAD;
  if (tid < 128) rsum[tid] = 0.f;
  #pragma unroll
  for (int it = 0; it < 4; ++it) {
    int idx = it * 512 + tid;
    int r = idx >> 4, c = (idx & 15) << 2;
    float4 f = *(const float4*)(qb + (size_t)r * D_HEAD + c);
    *(ushort4*)&qs[r][c] = make_ushort4(f2bf(f.x), f2bf(f.y), f2bf(f.z), f2bf(f.w));
  }
  f32x4 acc_o[2][2];
  const f32x4 zero4 = {0.f, 0.f, 0.f, 0.f};
  #pragma unroll
  for (int a = 0; a < 2; ++a)
    #pragma unroll
    for (int b = 0; b < 2; ++b) acc_o[a][b] = zero4;
  float psum[2][4] = {{0.f,0.f,0.f,0.f},{0.f,0.f,0.f,0.f}};
  __syncthreads();
  for (int kt = 0; kt < NKT; ++kt) {
    const int kb0 = kt * 64;
    #pragma unroll
    for (int it = 0; it < 2; ++it) {
      int idx = it * 512 + tid;
      int r = idx >> 4, c = (idx & 15) << 2;
      float4 f = *(const float4*)(kbp + (size_t)(kb0 + r) * D_HEAD + c);
      *(ushort4*)&ks[r][c] = make_ushort4(f2bf(f.x), f2bf(f.y), f2bf(f.z), f2bf(f.w));
      float4 g = *(const float4*)(vbp + (size_t)(kb0 + r) * D_HEAD + c);
      vt[c+0][r] = f2bf(g.x); vt[c+1][r] = f2bf(g.y);
      vt[c+2][r] = f2bf(g.z); vt[c+3][r] = f2bf(g.w);
    }
    __syncthreads();
    f32x4 sc[2][2];
    #pragma unroll
    for (int a = 0; a < 2; ++a)
      #pragma unroll
      for (int b = 0; b < 2; ++b) sc[a][b] = zero4;
    #pragma unroll
    for (int kk = 0; kk < 2; ++kk) {
      const int ke = kk * 32 + lh * 8;
      bf16x8 af[2], bfq[2];
      #pragma unroll
      for (int mt = 0; mt < 2; ++mt) af[mt] = ldfrag(&qs[wm*32 + mt*16 + lr][ke]);
      #pragma unroll
      for (int nt = 0; nt < 2; ++nt) bfq[nt] = ldfrag(&ks[wn*32 + nt*16 + lr][ke]);
      #pragma unroll
      for (int mt = 0; mt < 2; ++mt)
        #pragma unroll
        for (int nt = 0; nt < 2; ++nt)
          sc[mt][nt] = mfma16(af[mt], bfq[nt], sc[mt][nt]);
    }
    #pragma unroll
    for (int mt = 0; mt < 2; ++mt)
      #pragma unroll
      for (int nt = 0; nt < 2; ++nt)
        #pragma unroll
        for (int r = 0; r < 4; ++r) {
          int row = wm*32 + mt*16 + lh*4 + r, col = wn*32 + nt*16 + lr;
          int mv = maskg[(size_t)(br0 + row) * T_SEQ + (kb0 + col)];
          float p = mv ? __expf(sc[mt][nt][r] * scale) : 0.f;
          psum[mt][r] += p;
          pp[row][col] = f2bf(p);
        }
    __syncthreads();
    #pragma unroll
    for (int kk = 0; kk < 2; ++kk) {
      const int ke = kk * 32 + lh * 8;
      bf16x8 pa[2], vf[2];
      #pragma unroll
      for (int mt = 0; mt < 2; ++mt) pa[mt] = ldfrag(&pp[wm*32 + mt*16 + lr][ke]);
      #pragma unroll
      for (int nt = 0; nt < 2; ++nt) vf[nt] = ldfrag(&vt[wn*32 + nt*16 + lr][ke]);
      #pragma unroll
      for (int mt = 0; mt < 2; ++mt)
        #pragma unroll
        for (int nt = 0; nt < 2; ++nt)
          acc_o[mt][nt] = mfma16(pa[mt], vf[nt], acc_o[mt][nt]);
    }
    __syncthreads();
  }
  #pragma unroll
  for (int mt = 0; mt < 2; ++mt)
    #pragma unroll
    for (int r = 0; r < 4; ++r) {
      float sv = psum[mt][r];
      sv += __shfl_xor(sv, 1); sv += __shfl_xor(sv, 2);
      sv += __shfl_xor(sv, 4); sv += __shfl_xor(sv, 8);
      if (lr == 0) atomicAdd(&rsum[wm*32 + mt*16 + lh*4 + r], sv);
    }
  __syncthreads();
  float invs[2][4];
  #pragma unroll
  for (int mt = 0; mt < 2; ++mt)
    #pragma unroll
    for (int r = 0; r < 4; ++r)
      invs[mt][r] = 1.0f / rsum[wm*32 + mt*16 + lh*4 + r];
  float* ob = outg + ((size_t)bh * T_SEQ + br0) * D_HEAD;
  #pragma unroll
  for (int mt = 0; mt < 2; ++mt)
    #pragma unroll
    for (int nt = 0; nt < 2; ++nt)
      #pragma unroll
      for (int r = 0; r < 4; ++r) {
        int row = wm*32 + mt*16 + lh*4 + r, col = wn*32 + nt*16 + lr;
        ob[(size_t)row * D_HEAD + col] = acc_o[mt][nt][r] * invs[mt][r];
      }
  float* ab = attng + (size_t)bh * T_SEQ * T_SEQ + (size_t)br0 * T_SEQ;
  for (int kt = 0; kt < NKT; ++kt) {
    const int kb0 = kt * 64;
    __syncthreads();
    #pragma unroll
    for (int it = 0; it < 2; ++it) {
      int idx = it * 512 + tid;
      int r = idx >> 4, c = (idx & 15) << 2;
      float4 f = *(const float4*)(kbp + (size_t)(kb0 + r) * D_HEAD + c);
      *(ushort4*)&ks[r][c] = make_ushort4(f2bf(f.x), f2bf(f.y), f2bf(f.z), f2bf(f.w));
    }
    __syncthreads();
    f32x4 sc[2][2];
    #pragma unroll
    for (int a = 0; a < 2; ++a)
      #pragma unroll
      for (int b = 0; b < 2; ++b) sc[a][b] = zero4;
    #pragma unroll
    for (int kk = 0; kk < 2; ++kk) {
      const int ke = kk * 32 + lh * 8;
      bf16x8 af[2], bfq[2];
      #pragma unroll
      for (int mt = 0; mt < 2; ++mt) af[mt] = ldfrag(&qs[wm*32 + mt*16 + lr][ke]);
      #pragma unroll
      for (int nt = 0; nt < 2; ++nt) bfq[nt] = ldfrag(&ks[wn*32 + nt*16 + lr][ke]);
      #pragma unroll
      for (int mt = 0; mt < 2; ++mt)
        #pragma unroll
        for (int nt = 0; nt < 2; ++nt)
          sc[mt][nt] = mfma16(af[mt], bfq[nt], sc[mt][nt]);
    }
    #pragma unroll
    for (int mt = 0; mt < 2; ++mt)
      #pragma unroll
      for (int nt = 0; nt < 2; ++nt)
        #pragma unroll
        for (int r = 0; r < 4; ++r) {
          int row = wm*32 + mt*16 + lh*4 + r, col = wn*32 + nt*16 + lr;
          int mv = maskg[(size_t)(br0 + row) * T_SEQ + (kb0 + col)];
          float p = mv ? __expf(sc[mt][nt][r] * scale) * invs[mt][r] : 0.f;
          ab[(size_t)row * T_SEQ + kb0 + col] = p;
        }
  }
}

extern "C" void kernel_launch(void* const* d_in, const int* in_sizes, int n_in,
                              void* d_out, int out_size, void* d_ws, size_t ws_size,
                              hipStream_t stream) {
  const float* q = (const float*)d_in[0];
  const float* k = (const float*)d_in[1];
  const float* v = (const float*)d_in[2];
  const int* mask = (const int*)d_in[3];
  float* out = (float*)d_out;
  float* attn = out + (size_t)2 * 16 * T_SEQ * D_HEAD;

  const size_t mpk_bytes = (size_t)T_SEQ * T_SEQ / 8;   // 512 KB
  if (ws_size >= mpk_bytes) {
    unsigned* mp = (unsigned*)d_ws;
    mask_pack<<<dim3(2048), 256, 0, stream>>>(mask, mp);
    attn_fused5<<<dim3(1024), NTHR, 0, stream>>>(q, k, v, mp, out, attn);
  } else {
    attn_fused_fb<<<dim3(512), 512, 0, stream>>>(q, k, v, mask, out, attn);
  }
}

// Round 13
// 189.352 us; speedup vs baseline: 1.2722x; 1.2722x over previous
//
#include <hip/hip_runtime.h>
#include <hip/hip_bf16.h>
#include <cstddef>

#define T_SEQ 2048
#define D_HEAD 64
#define BC 64
#define NKT (T_SEQ / BC)
#define PAD 72           // LDS row stride elems (144 B, 16B-aligned)

typedef __bf16 bf16x8 __attribute__((ext_vector_type(8)));
typedef float f32x4 __attribute__((ext_vector_type(4)));
typedef unsigned short u16x8 __attribute__((ext_vector_type(8)));

__device__ __forceinline__ unsigned short f2bf(float f) {
  __bf16 h = (__bf16)f;
  return __builtin_bit_cast(unsigned short, h);
}
__device__ __forceinline__ bf16x8 ldfrag(const unsigned short* p) {
  u16x8 t = *(const u16x8*)p;
  return __builtin_bit_cast(bf16x8, t);
}
__device__ __forceinline__ f32x4 mfma16(bf16x8 a, bf16x8 b, f32x4 c) {
  return __builtin_amdgcn_mfma_f32_16x16x32_bf16(a, b, c, 0, 0, 0);
}
__device__ __forceinline__ void bar_sync() {
  asm volatile("" ::: "memory");
  __builtin_amdgcn_s_barrier();
  asm volatile("" ::: "memory");
}
__device__ __forceinline__ void lds_fence() {
  asm volatile("s_waitcnt lgkmcnt(0)" ::: "memory");
}
__device__ __forceinline__ float exp2_hw(float x) { return __builtin_amdgcn_exp2f(x); }
__device__ __forceinline__ float log2_hw(float x) { return __builtin_amdgcn_logf(x); }

// ---------- mask pack: (T,T) int32 {0,1} -> 1 bit/elem ----------
__global__ __launch_bounds__(256) void mask_pack(const int* __restrict__ maskg,
                                                 unsigned* __restrict__ mp) {
  const size_t total = (size_t)T_SEQ * T_SEQ;
  size_t idx = (size_t)blockIdx.x * blockDim.x + threadIdx.x;
  const size_t stride = (size_t)gridDim.x * blockDim.x;
  const int lane = threadIdx.x & 63;
  for (; idx < total; idx += stride) {
    int mv = maskg[idx];
    unsigned long long b = __ballot(mv != 0);
    if (lane == 0)       mp[idx >> 5] = (unsigned)b;
    else if (lane == 32) mp[idx >> 5] = (unsigned)(b >> 32);
  }
}

// ---------- R9 structure + b128 K staging + b64 P writes ----------
// frag convention (verified R1-R9): A/B-frag row=lane&15, k=kk*32+8*(lane>>4)+[0..7]
// mfma(A,B): D[aidx][bidx], row=4*(lane>>4)+reg -> aidx, col=lane&15 -> bidx
__global__ __launch_bounds__(256, 5) void attn_fused2(
    const float* __restrict__ qg, const float* __restrict__ kg,
    const float* __restrict__ vg, const unsigned* __restrict__ mpk,
    float* __restrict__ outg, float* __restrict__ attng)
{
  __shared__ unsigned short ks[BC][PAD];      // K tile bf16 [key][d]
  __shared__ unsigned short vt[D_HEAD][PAD];  // V^T tile bf16 [d][key]
  __shared__ unsigned short ps[64][PAD];      // P [q-striplocal][key], wave-private bands

  const int bid = blockIdx.x;
  const int lin = (bid & 7) * 128 + (bid >> 3);   // XCD-chunked: 4 heads/XCD
  const int bh  = lin >> 5;                       // head 0..31
  const int strip = lin & 31;                     // q-strip (64 rows)

  const int tid  = threadIdx.x;
  const int lane = tid & 63;
  const int wid  = tid >> 6;                      // 0..3
  const int lr = lane & 15, lh = lane >> 4;
  const int r0 = strip * 64 + wid * 16;           // head-local q-row base (wave)
  const int sv = tid >> 2;                        // K staging row 0..63
  const int sc4 = (tid & 3) << 4;                 // K staging col {0,16,32,48}
  const int vt7 = tid & 7;                        // V staging: d = vt7 + 8j
  const int vs2 = (tid >> 3) * 2;                 // V staging: s pair

  const float C = 0.18033688011112042f;           // 0.125 * log2(e)
  const float* qb = qg + (size_t)bh * T_SEQ * D_HEAD;
  const float* kb = kg + (size_t)bh * T_SEQ * D_HEAD;
  const float* vb = vg + (size_t)bh * T_SEQ * D_HEAD;
  const int ROWW = T_SEQ / 32;
  const f32x4 zero4 = {0.f, 0.f, 0.f, 0.f};

  // ---- Q frags into registers (once) ----
  bf16x8 qf[2];
  {
    const float* qr = qb + (size_t)(r0 + lr) * D_HEAD;
    #pragma unroll
    for (int kk = 0; kk < 2; ++kk) {
      float4 a = *(const float4*)(qr + kk * 32 + lh * 8);
      float4 b = *(const float4*)(qr + kk * 32 + lh * 8 + 4);
      u16x8 u;
      u[0] = f2bf(a.x); u[1] = f2bf(a.y); u[2] = f2bf(a.z); u[3] = f2bf(a.w);
      u[4] = f2bf(b.x); u[5] = f2bf(b.y); u[6] = f2bf(b.z); u[7] = f2bf(b.w);
      qf[kk] = __builtin_bit_cast(bf16x8, u);
    }
  }

  f32x4 acc[4];
  #pragma unroll
  for (int nt = 0; nt < 4; ++nt) acc[nt] = zero4;
  float psum_s = 0.f;    // rowsum for q = r0 + lr (swapped layout)

  // =================== PASS 1 (swapped QK^T, 2 barriers/tile) ===================
  for (int kt = 0; kt < NKT; ++kt) {
    const int n0 = kt * BC;
    bar_sync();                                  // LDS free (prev tile consumed)
    // stage K row-major (2 x b128, clean)
    {
      const float* ksrc = kb + (size_t)(n0 + sv) * D_HEAD + sc4;
      float4 k0 = *(const float4*)(ksrc + 0),  k1 = *(const float4*)(ksrc + 4);
      float4 k2 = *(const float4*)(ksrc + 8),  k3 = *(const float4*)(ksrc + 12);
      u16x8 w0, w1;
      w0[0]=f2bf(k0.x); w0[1]=f2bf(k0.y); w0[2]=f2bf(k0.z); w0[3]=f2bf(k0.w);
      w0[4]=f2bf(k1.x); w0[5]=f2bf(k1.y); w0[6]=f2bf(k1.z); w0[7]=f2bf(k1.w);
      w1[0]=f2bf(k2.x); w1[1]=f2bf(k2.y); w1[2]=f2bf(k2.z); w1[3]=f2bf(k2.w);
      w1[4]=f2bf(k3.x); w1[5]=f2bf(k3.y); w1[6]=f2bf(k3.z); w1[7]=f2bf(k3.w);
      *(u16x8*)&ks[sv][sc4 + 0] = w0;
      *(u16x8*)&ks[sv][sc4 + 8] = w1;
    }
    // stage V^T as packed s-pairs (8 x b32, 2-way banks = free)
    {
      const float* v0 = vb + (size_t)(n0 + vs2) * D_HEAD + vt7;
      const float* v1 = v0 + D_HEAD;
      #pragma unroll
      for (int j = 0; j < 8; ++j) {
        const float a = v0[8 * j];
        const float b = v1[8 * j];
        const unsigned w = (unsigned)f2bf(a) | ((unsigned)f2bf(b) << 16);
        *(unsigned*)&vt[vt7 + 8 * j][vs2] = w;
      }
    }
    // mask: 2 words for this thread's q-row (q = r0 + lr), head-local
    const unsigned mw0 = mpk[(size_t)(r0 + lr) * ROWW + kt * 2];
    const unsigned mw1 = mpk[(size_t)(r0 + lr) * ROWW + kt * 2 + 1];
    lds_fence(); bar_sync();                     // tile ready

    // swapped QK^T: st[nt] = S^T, thread holds P[key=nt*16+4lh+r][q=lr]
    f32x4 st[4];
    #pragma unroll
    for (int nt = 0; nt < 4; ++nt) st[nt] = zero4;
    #pragma unroll
    for (int kk = 0; kk < 2; ++kk) {
      bf16x8 kf[4];
      #pragma unroll
      for (int nt = 0; nt < 4; ++nt) kf[nt] = ldfrag(&ks[nt * 16 + lr][kk * 32 + lh * 8]);
      #pragma unroll
      for (int nt = 0; nt < 4; ++nt) st[nt] = mfma16(kf[nt], qf[kk], st[nt]);
    }
    // mask + exp + psum + packed P write (4 x b64)
    #pragma unroll
    for (int nt = 0; nt < 4; ++nt) {
      const unsigned w = (nt & 2) ? mw1 : mw0;
      float p[4];
      #pragma unroll
      for (int r = 0; r < 4; ++r) {
        const int bit = (nt & 1) * 16 + 4 * lh + r;
        p[r] = ((w >> bit) & 1) ? exp2_hw(st[nt][r] * C) : 0.f;
        psum_s += p[r];
      }
      uint2 u;
      u.x = (unsigned)f2bf(p[0]) | ((unsigned)f2bf(p[1]) << 16);
      u.y = (unsigned)f2bf(p[2]) | ((unsigned)f2bf(p[3]) << 16);
      *(uint2*)&ps[wid * 16 + lr][nt * 16 + 4 * lh] = u;
    }
    lds_fence();                                 // wave-private write->read
    // PV: A = P rows (q=lr), B = V^T rows (d)
    #pragma unroll
    for (int kk = 0; kk < 2; ++kk) {
      const bf16x8 pa = ldfrag(&ps[wid * 16 + lr][kk * 32 + lh * 8]);
      #pragma unroll
      for (int nt = 0; nt < 4; ++nt) {
        const bf16x8 vf = ldfrag(&vt[nt * 16 + lr][kk * 32 + lh * 8]);
        acc[nt] = mfma16(pa, vf, acc[nt]);
      }
    }
  }

  // rowsum for q = lr: reduce across the 4 lh-lanes
  psum_s += __shfl_xor(psum_s, 16);
  psum_s += __shfl_xor(psum_s, 32);
  const float iv_s = 1.0f / psum_s;
  // redistribute: iv for q = 4lh + r  (src lane 4lh+r has lr = 4lh+r)
  float ivq[4], lg2ivq[4];
  #pragma unroll
  for (int r = 0; r < 4; ++r) {
    ivq[r] = __shfl(iv_s, 4 * lh + r);
    lg2ivq[r] = log2_hw(ivq[r]);
  }

  // O write: acc layout row(q)=4lh+r, col(d)=nt*16+lr
  float* ob = outg + (size_t)(bh * T_SEQ + r0) * D_HEAD;
  #pragma unroll
  for (int nt = 0; nt < 4; ++nt)
    #pragma unroll
    for (int r = 0; r < 4; ++r)
      ob[(size_t)(4 * lh + r) * D_HEAD + nt * 16 + lr] = acc[nt][r] * ivq[r];

  // =================== PASS 2 (direct QK^T, coalesced stores) ===================
  float* ab = attng + (size_t)(bh * T_SEQ + r0) * T_SEQ;
  for (int kt = 0; kt < NKT; ++kt) {
    const int n0 = kt * BC;
    bar_sync();
    {
      const float* ksrc = kb + (size_t)(n0 + sv) * D_HEAD + sc4;
      float4 k0 = *(const float4*)(ksrc + 0),  k1 = *(const float4*)(ksrc + 4);
      float4 k2 = *(const float4*)(ksrc + 8),  k3 = *(const float4*)(ksrc + 12);
      u16x8 w0, w1;
      w0[0]=f2bf(k0.x); w0[1]=f2bf(k0.y); w0[2]=f2bf(k0.z); w0[3]=f2bf(k0.w);
      w0[4]=f2bf(k1.x); w0[5]=f2bf(k1.y); w0[6]=f2bf(k1.z); w0[7]=f2bf(k1.w);
      w1[0]=f2bf(k2.x); w1[1]=f2bf(k2.y); w1[2]=f2bf(k2.z); w1[3]=f2bf(k2.w);
      w1[4]=f2bf(k3.x); w1[5]=f2bf(k3.y); w1[6]=f2bf(k3.z); w1[7]=f2bf(k3.w);
      *(u16x8*)&ks[sv][sc4 + 0] = w0;
      *(u16x8*)&ks[sv][sc4 + 8] = w1;
    }
    unsigned mw[4][2];
    #pragma unroll
    for (int r = 0; r < 4; ++r) {
      const size_t mrow = (size_t)(r0 + 4 * lh + r) * ROWW + kt * 2;  // head-local
      mw[r][0] = mpk[mrow];
      mw[r][1] = mpk[mrow + 1];
    }
    lds_fence(); bar_sync();

    f32x4 sc_[4];
    #pragma unroll
    for (int nt = 0; nt < 4; ++nt) sc_[nt] = zero4;
    #pragma unroll
    for (int kk = 0; kk < 2; ++kk) {
      bf16x8 kf[4];
      #pragma unroll
      for (int nt = 0; nt < 4; ++nt) kf[nt] = ldfrag(&ks[nt * 16 + lr][kk * 32 + lh * 8]);
      #pragma unroll
      for (int nt = 0; nt < 4; ++nt) sc_[nt] = mfma16(qf[kk], kf[nt], sc_[nt]);
    }
    #pragma unroll
    for (int r = 0; r < 4; ++r) {
      float* arow = ab + (size_t)(4 * lh + r) * T_SEQ + n0;
      #pragma unroll
      for (int nt = 0; nt < 4; ++nt) {
        const int mv = (mw[r][nt >> 1] >> ((nt & 1) * 16 + lr)) & 1;
        const float p = mv ? exp2_hw(__builtin_fmaf(sc_[nt][r], C, lg2ivq[r])) : 0.f;
        __builtin_nontemporal_store(p, arow + nt * 16 + lr);
      }
    }
  }
}

// ---------- fallback: fused single kernel, raw mask (ws too small) ----------
__global__ __launch_bounds__(512, 2) void attn_fused_fb(
    const float* __restrict__ qg, const float* __restrict__ kg,
    const float* __restrict__ vg, const int* __restrict__ maskg,
    float* __restrict__ outg, float* __restrict__ attng)
{
  __shared__ unsigned short qs[128][PAD];
  __shared__ unsigned short ks[64][PAD];
  __shared__ unsigned short vt[64][PAD];
  __shared__ unsigned short pp[128][PAD];
  __shared__ float rsum[128];
  int bid = blockIdx.x;
  int lin = (bid & 7) * 64 + (bid >> 3);
  int bh = lin >> 4, br0 = (lin & 15) * 128;
  const int tid = threadIdx.x, lane = tid & 63, wid = tid >> 6;
  const int wm = wid >> 1, wn = wid & 1, lr = lane & 15, lh = lane >> 4;
  const float scale = 0.125f;
  const float* qb = qg + ((size_t)bh * T_SEQ + br0) * D_HEAD;
  const float* kbp = kg + (size_t)bh * T_SEQ * D_HEAD;
  const float* vbp = vg + (size_t)bh * T_SEQ * D_HEAD;
  if (tid < 128) rsum[tid] = 0.f;
  #pragma unroll
  for (int it = 0; it < 4; ++it) {
    int idx = it * 512 + tid;
    int r = idx >> 4, c = (idx & 15) << 2;
    float4 f = *(const float4*)(qb + (size_t)r * D_HEAD + c);
    *(ushort4*)&qs[r][c] = make_ushort4(f2bf(f.x), f2bf(f.y), f2bf(f.z), f2bf(f.w));
  }
  f32x4 acc_o[2][2];
  const f32x4 zero4 = {0.f, 0.f, 0.f, 0.f};
  #pragma unroll
  for (int a = 0; a < 2; ++a)
    #pragma unroll
    for (int b = 0; b < 2; ++b) acc_o[a][b] = zero4;
  float psum[2][4] = {{0.f,0.f,0.f,0.f},{0.f,0.f,0.f,0.f}};
  __syncthreads();
  for (int kt = 0; kt < NKT; ++kt) {
    const int kb0 = kt * 64;
    #pragma unroll
    for (int it = 0; it < 2; ++it) {
      int idx = it * 512 + tid;
      int r = idx >> 4, c = (idx & 15) << 2;
      float4 f = *(const float4*)(kbp + (size_t)(kb0 + r) * D_HEAD + c);
      *(ushort4*)&ks[r][c] = make_ushort4(f2bf(f.x), f2bf(f.y), f2bf(f.z), f2bf(f.w));
      float4 g = *(const float4*)(vbp + (size_t)(kb0 + r) * D_HEAD + c);
      vt[c+0][r] = f2bf(g.x); vt[c+1][r] = f2bf(g.y);
      vt[c+2][r] = f2bf(g.z); vt[c+3][r] = f2bf(g.w);
    }
    __syncthreads();
    f32x4 sc[2][2];
    #pragma unroll
    for (int a = 0; a < 2; ++a)
      #pragma unroll
      for (int b = 0; b < 2; ++b) sc[a][b] = zero4;
    #pragma unroll
    for (int kk = 0; kk < 2; ++kk) {
      const int ke = kk * 32 + lh * 8;
      bf16x8 af[2], bfq[2];
      #pragma unroll
      for (int mt = 0; mt < 2; ++mt) af[mt] = ldfrag(&qs[wm*32 + mt*16 + lr][ke]);
      #pragma unroll
      for (int nt = 0; nt < 2; ++nt) bfq[nt] = ldfrag(&ks[wn*32 + nt*16 + lr][ke]);
      #pragma unroll
      for (int mt = 0; mt < 2; ++mt)
        #pragma unroll
        for (int nt = 0; nt < 2; ++nt)
          sc[mt][nt] = mfma16(af[mt], bfq[nt], sc[mt][nt]);
    }
    #pragma unroll
    for (int mt = 0; mt < 2; ++mt)
      #pragma unroll
      for (int nt = 0; nt < 2; ++nt)
        #pragma unroll
        for (int r = 0; r < 4; ++r) {
          int row = wm*32 + mt*16 + lh*4 + r, col = wn*32 + nt*16 + lr;
          int mv = maskg[(size_t)(br0 + row) * T_SEQ + (kb0 + col)];
          float p = mv ? __expf(sc[mt][nt][r] * scale) : 0.f;
          psum[mt][r] += p;
          pp[row][col] = f2bf(p);
        }
    __syncthreads();
    #pragma unroll
    for (int kk = 0; kk < 2; ++kk) {
      const int ke = kk * 32 + lh * 8;
      bf16x8 pa[2], vf[2];
      #pragma unroll
      for (int mt = 0; mt < 2; ++mt) pa[mt] = ldfrag(&pp[wm*32 + mt*16 + lr][ke]);
      #pragma unroll
      for (int nt = 0; nt < 2; ++nt) vf[nt] = ldfrag(&vt[wn*32 + nt*16 + lr][ke]);
      #pragma unroll
      for (int mt = 0; mt < 2; ++mt)
        #pragma unroll
        for (int nt = 0; nt < 2; ++nt)
          acc_o[mt][nt] = mfma16(pa[mt], vf[nt], acc_o[mt][nt]);
    }
    __syncthreads();
  }
  #pragma unroll
  for (int mt = 0; mt < 2; ++mt)
    #pragma unroll
    for (int r = 0; r < 4; ++r) {
      float sv = psum[mt][r];
      sv += __shfl_xor(sv, 1); sv += __shfl_xor(sv, 2);
      sv += __shfl_xor(sv, 4); sv += __shfl_xor(sv, 8);
      if (lr == 0) atomicAdd(&rsum[wm*32 + mt*16 + lh*4 + r], sv);
    }
  __syncthreads();
  float invs[2][4];
  #pragma unroll
  for (int mt = 0; mt < 2; ++mt)
    #pragma unroll
    for (int r = 0; r < 4; ++r)
      invs[mt][r] = 1.0f / rsum[wm*32 + mt*16 + lh*4 + r];
  float* ob = outg + ((size_t)bh * T_SEQ + br0) * D_HEAD;
  #pragma unroll
  for (int mt = 0; mt < 2; ++mt)
    #pragma unroll
    for (int nt = 0; nt < 2; ++nt)
      #pragma unroll
      for (int r = 0; r < 4; ++r) {
        int row = wm*32 + mt*16 + lh*4 + r, col = wn*32 + nt*16 + lr;
        ob[(size_t)row * D_HEAD + col] = acc_o[mt][nt][r] * invs[mt][r];
      }
  float* ab = attng + (size_t)bh * T_SEQ * T_SEQ + (size_t)br0 * T_SEQ;
  for (int kt = 0; kt < NKT; ++kt) {
    const int kb0 = kt * 64;
    __syncthreads();
    #pragma unroll
    for (int it = 0; it < 2; ++it) {
      int idx = it * 512 + tid;
      int r = idx >> 4, c = (idx & 15) << 2;
      float4 f = *(const float4*)(kbp + (size_t)(kb0 + r) * D_HEAD + c);
      *(ushort4*)&ks[r][c] = make_ushort4(f2bf(f.x), f2bf(f.y), f2bf(f.z), f2bf(f.w));
    }
    __syncthreads();
    f32x4 sc[2][2];
    #pragma unroll
    for (int a = 0; a < 2; ++a)
      #pragma unroll
      for (int b = 0; b < 2; ++b) sc[a][b] = zero4;
    #pragma unroll
    for (int kk = 0; kk < 2; ++kk) {
      const int ke = kk * 32 + lh * 8;
      bf16x8 af[2], bfq[2];
      #pragma unroll
      for (int mt = 0; mt < 2; ++mt) af[mt] = ldfrag(&qs[wm*32 + mt*16 + lr][ke]);
      #pragma unroll
      for (int nt = 0; nt < 2; ++nt) bfq[nt] = ldfrag(&ks[wn*32 + nt*16 + lr][ke]);
      #pragma unroll
      for (int mt = 0; mt < 2; ++mt)
        #pragma unroll
        for (int nt = 0; nt < 2; ++nt)
          sc[mt][nt] = mfma16(af[mt], bfq[nt], sc[mt][nt]);
    }
    #pragma unroll
    for (int mt = 0; mt < 2; ++mt)
      #pragma unroll
      for (int nt = 0; nt < 2; ++nt)
        #pragma unroll
        for (int r = 0; r < 4; ++r) {
          int row = wm*32 + mt*16 + lh*4 + r, col = wn*32 + nt*16 + lr;
          int mv = maskg[(size_t)(br0 + row) * T_SEQ + (kb0 + col)];
          float p = mv ? __expf(sc[mt][nt][r] * scale) * invs[mt][r] : 0.f;
          ab[(size_t)row * T_SEQ + kb0 + col] = p;
        }
  }
}

extern "C" void kernel_launch(void* const* d_in, const int* in_sizes, int n_in,
                              void* d_out, int out_size, void* d_ws, size_t ws_size,
                              hipStream_t stream) {
  const float* q = (const float*)d_in[0];
  const float* k = (const float*)d_in[1];
  const float* v = (const float*)d_in[2];
  const int* mask = (const int*)d_in[3];
  float* out = (float*)d_out;
  float* attn = out + (size_t)2 * 16 * T_SEQ * D_HEAD;

  const size_t mpk_bytes = (size_t)T_SEQ * T_SEQ / 8;   // 512 KB
  if (ws_size >= mpk_bytes) {
    unsigned* mp = (unsigned*)d_ws;
    mask_pack<<<dim3(2048), 256, 0, stream>>>(mask, mp);
    attn_fused2<<<dim3(1024), 256, 0, stream>>>(q, k, v, mp, out, attn);
  } else {
    attn_fused_fb<<<dim3(512), 512, 0, stream>>>(q, k, v, mask, out, attn);
  }
}